// Round 12
// baseline (164.999 us; speedup 1.0000x reference)
//
#include <hip/hip_runtime.h>
#include <stdint.h>

typedef unsigned short u16;
typedef unsigned int u32;
typedef __attribute__((ext_vector_type(8))) short short8;
typedef __attribute__((ext_vector_type(4))) float float4v;

#define Bb 4
#define Ss 256
#define Hh 768
#define NALL 64
#define GRID2 1024        // 4 blocks/CU co-resident (LDS 18.4K*4=74K, VGPR<=128)
#define MAGIC 0x1234ABCD

// Inputs/outputs are FP32 (reference dtype; established r7).

__device__ __forceinline__ u16 f2b(float f) {
    u32 u;
    __builtin_memcpy(&u, &f, 4);
    u = (u + 0x7fffu + ((u >> 16) & 1u)) >> 16;  // RNE
    return (u16)u;
}
union pk8 { uint4 v; u16 e[8]; };
__device__ __forceinline__ uint4 cvt8(float4 f0, float4 f1) {
    pk8 r;
    r.e[0] = f2b(f0.x); r.e[1] = f2b(f0.y); r.e[2] = f2b(f0.z); r.e[3] = f2b(f0.w);
    r.e[4] = f2b(f1.x); r.e[5] = f2b(f1.y); r.e[6] = f2b(f1.z); r.e[7] = f2b(f1.w);
    return r.v;
}

// s_sleep arg must be a compile-time constant (r11 compile fail).
// Fixed 16 => 1024 cycles (~0.43us) per poll; 1024 read-only pollers
// ~2.4M polls/s aggregate on one line — no congestion.
__device__ __forceinline__ void poll_eq(int* p, int val) {
    if (__hip_atomic_load(p, __ATOMIC_RELAXED, __HIP_MEMORY_SCOPE_AGENT) == val) return;
    __builtin_amdgcn_s_sleep(2);
    while (__hip_atomic_load(p, __ATOMIC_RELAXED, __HIP_MEMORY_SCOPE_AGENT) != val)
        __builtin_amdgcn_s_sleep(16);
}

// ---- Launch 1: basicT transpose + coefC build (fully parallel, no sync) ----
__global__ __launch_bounds__(256) void k_prep2(const int* __restrict__ rels,
                                               const float* __restrict__ basic,
                                               const float* __restrict__ relw,
                                               u16* __restrict__ basicT,
                                               u16* __restrict__ coefC) {
    __shared__ u16 tile[32][34];
    __shared__ float srelw[256];
    __shared__ u32 hist[NALL];
    const int z = blockIdx.x;
    const int t = threadIdx.x;

    if (z < 2304) {                     // basicT[q][o][i] = bf16(basic[q][i][o])
        const int q = z / 576, rem = z % 576;
        const int i0 = (rem % 24) * 32, o0 = (rem / 24) * 32;
        const int tx = t & 31, ty = t >> 5;
        const size_t base = (size_t)q * Hh * Hh;
#pragma unroll
        for (int r = 0; r < 4; ++r)
            tile[ty + 8 * r][tx] = f2b(basic[base + (size_t)(i0 + ty + 8 * r) * Hh + o0 + tx]);
        __syncthreads();
#pragma unroll
        for (int r = 0; r < 4; ++r)
            basicT[base + (size_t)(o0 + ty + 8 * r) * Hh + i0 + tx] = tile[tx][ty + 8 * r];
    } else {                            // coefC: one block per (b,i)
        const int r = z - 2304;
        const int i = r & 255, b = r >> 8;
        srelw[t] = relw[t];
        if (t < NALL) hist[t] = 0u;
        __syncthreads();
        const int rfw = rels[(b * Ss + i) * Ss + t];
        const int rcl = rels[(b * Ss + t) * Ss + i];
        if (rfw > 0) atomicAdd(&hist[rfw], 1u);
        if (rcl > 0) atomicAdd(&hist[rcl + 32], 1u);
        __syncthreads();
        float c0 = 0.f, c1 = 0.f, c2 = 0.f, c3 = 0.f;
        if (rfw > 0) {
            const float inv = 1.0f / (float)hist[rfw];
            c0 += srelw[rfw * 4 + 0] * inv; c1 += srelw[rfw * 4 + 1] * inv;
            c2 += srelw[rfw * 4 + 2] * inv; c3 += srelw[rfw * 4 + 3] * inv;
        }
        if (rcl > 0) {
            const int rr = rcl + 32;
            const float inv = 1.0f / (float)hist[rr];
            c0 += srelw[rr * 4 + 0] * inv; c1 += srelw[rr * 4 + 1] * inv;
            c2 += srelw[rr * 4 + 2] * inv; c3 += srelw[rr * 4 + 3] * inv;
        }
        const size_t base = ((size_t)(b * 4) * Ss + i) * Ss + t;
        coefC[base] = f2b(c0);
        coefC[base + (size_t)Ss * Ss] = f2b(c1);
        coefC[base + (size_t)2 * Ss * Ss] = f2b(c2);
        coefC[base + (size_t)3 * Ss * Ss] = f2b(c3);
    }
}

// ---- Launch 2: Gt GEMM | barrier | out GEMM ----
__global__ __launch_bounds__(256, 4) void k_fused2(const float* __restrict__ h,
                                                   const float* __restrict__ selfw,
                                                   const u16* __restrict__ basicT,
                                                   const u16* __restrict__ coefC,
                                                   u16* __restrict__ Gt,
                                                   int* __restrict__ bar,
                                                   float* __restrict__ out) {
    __shared__ __align__(16) u16 As[64 * 72];
    __shared__ __align__(16) u16 Bs[64 * 72];
    const int t = threadIdx.x;
    const int row = t >> 2, kk = (t & 3) * 16;
    const int w = t >> 6, l = t & 63, quad = l >> 4, l16 = l & 15;

    if (blockIdx.x == 0 && t == 0) {
        __hip_atomic_store(&bar[32], 0, __ATOMIC_RELAXED, __HIP_MEMORY_SCOPE_AGENT);  // arrivals
        __hip_atomic_store(&bar[64], 0, __ATOMIC_RELAXED, __HIP_MEMORY_SCOPE_AGENT);  // release flag
        __hip_atomic_store(&bar[0], MAGIC, __ATOMIC_RELEASE, __HIP_MEMORY_SCOPE_AGENT);
    }

    // -------- phase alpha: Gt[bk][o][j] = sum_i basicT[q][o][i] * h[b][j][i] --------
    if (blockIdx.x < 768) {
        const int u = blockIdx.x;
        const int o0 = (u % 12) * 64, j0 = ((u / 12) % 4) * 64, bk = u / 48;
        const int b = bk >> 2, q = bk & 3;
        const u16* aB = basicT + ((size_t)q * Hh + o0 + row) * Hh + kk;       // bf16
        const float* bB = h + ((size_t)b * Ss + j0 + row) * Hh + kk;          // fp32
        float4v acc[4];
#pragma unroll
        for (int c = 0; c < 4; ++c) acc[c] = (float4v){0.f, 0.f, 0.f, 0.f};
        uint4 a0 = *(const uint4*)aB, a1 = *(const uint4*)(aB + 8);
        float4 f0 = *(const float4*)bB, f1 = *(const float4*)(bB + 4);
        float4 f2 = *(const float4*)(bB + 8), f3 = *(const float4*)(bB + 12);
        for (int s = 0; s < 12; ++s) {
            __syncthreads();
            *(uint4*)(&As[row * 72 + kk]) = a0;
            *(uint4*)(&As[row * 72 + kk + 8]) = a1;
            *(uint4*)(&Bs[row * 72 + kk]) = cvt8(f0, f1);      // cvt deferred to staging
            *(uint4*)(&Bs[row * 72 + kk + 8]) = cvt8(f2, f3);
            __syncthreads();
            if (s + 1 < 12) {
                a0 = *(const uint4*)(aB + (s + 1) * 64);
                a1 = *(const uint4*)(aB + (s + 1) * 64 + 8);
                const float* bp = bB + (s + 1) * 64;
                f0 = *(const float4*)bp;      f1 = *(const float4*)(bp + 4);
                f2 = *(const float4*)(bp + 8); f3 = *(const float4*)(bp + 12);
            }
#pragma unroll
            for (int k2 = 0; k2 < 64; k2 += 32) {
                const short8 af = *(const short8*)(&As[(16 * w + l16) * 72 + k2 + quad * 8]);
#pragma unroll
                for (int c = 0; c < 4; ++c) {
                    const short8 bfr = *(const short8*)(&Bs[(16 * c + l16) * 72 + k2 + quad * 8]);
                    acc[c] = __builtin_amdgcn_mfma_f32_16x16x32_bf16(af, bfr, acc[c], 0, 0, 0);
                }
            }
        }
#pragma unroll
        for (int c = 0; c < 4; ++c)
#pragma unroll
            for (int r = 0; r < 4; ++r) {
                const int ol = 16 * w + quad * 4 + r;
                const int jl = 16 * c + l16;
                Gt[((size_t)bk * Hh + o0 + ol) * Ss + j0 + jl] = f2b(acc[c][r]);
            }
    }

    // -------- barrier: split poll line from arrival line (r9/r10 lesson) --------
    __syncthreads();
    if (t == 0) {
        poll_eq(&bar[0], MAGIC);                 // init visible
        const int old = __hip_atomic_fetch_add(&bar[32], 1, __ATOMIC_RELEASE, __HIP_MEMORY_SCOPE_AGENT);
        if (old == GRID2 - 1)
            __hip_atomic_store(&bar[64], MAGIC, __ATOMIC_RELEASE, __HIP_MEMORY_SCOPE_AGENT);
        poll_eq(&bar[64], MAGIC);                // read-only poll, fixed sleep
        __builtin_amdgcn_fence(__ATOMIC_ACQUIRE, "agent");
    }
    __syncthreads();

    // -------- phase beta: out = coefC@Gt (K=1024) + h@selfw^T (K=768) --------
    // workers on blockIdx % 5 == 0 -> spread across all CUs after others exit
    if (blockIdx.x % 5 == 0 && blockIdx.x / 5 < 192) {
        const int z = blockIdx.x / 5;
        const int ot = z % 12, it = (z / 12) % 4, b = z / 48;
        uint4 ua0, ua1, ub0, ub1;
        float4 fa0, fa1, fa2, fa3, fb0, fb1, fb2, fb3;
        bool af32 = false, bf32 = false;
        auto loadA = [&](int s) {
            if (s < 16) {
                const u16* p = coefC + ((size_t)(b * 4 + (s >> 2)) * Ss + it * 64 + row) * Ss + (s & 3) * 64 + kk;
                ua0 = *(const uint4*)p; ua1 = *(const uint4*)(p + 8); af32 = false;
            } else {
                const float* p = h + ((size_t)b * Ss + it * 64 + row) * Hh + (s - 16) * 64 + kk;
                fa0 = *(const float4*)p;      fa1 = *(const float4*)(p + 4);
                fa2 = *(const float4*)(p + 8); fa3 = *(const float4*)(p + 12); af32 = true;
            }
        };
        auto loadB = [&](int s) {
            if (s < 16) {
                const u16* p = Gt + ((size_t)(b * 4 + (s >> 2)) * Hh + ot * 64 + row) * Ss + (s & 3) * 64 + kk;
                ub0 = *(const uint4*)p; ub1 = *(const uint4*)(p + 8); bf32 = false;
            } else {
                const float* p = selfw + (size_t)(ot * 64 + row) * Hh + (s - 16) * 64 + kk;
                fb0 = *(const float4*)p;      fb1 = *(const float4*)(p + 4);
                fb2 = *(const float4*)(p + 8); fb3 = *(const float4*)(p + 12); bf32 = true;
            }
        };
        float4v acc[4];
#pragma unroll
        for (int c = 0; c < 4; ++c) acc[c] = (float4v){0.f, 0.f, 0.f, 0.f};
        loadA(0); loadB(0);
        for (int s = 0; s < 28; ++s) {
            __syncthreads();
            if (af32) {
                *(uint4*)(&As[row * 72 + kk]) = cvt8(fa0, fa1);
                *(uint4*)(&As[row * 72 + kk + 8]) = cvt8(fa2, fa3);
            } else {
                *(uint4*)(&As[row * 72 + kk]) = ua0;
                *(uint4*)(&As[row * 72 + kk + 8]) = ua1;
            }
            if (bf32) {
                *(uint4*)(&Bs[row * 72 + kk]) = cvt8(fb0, fb1);
                *(uint4*)(&Bs[row * 72 + kk + 8]) = cvt8(fb2, fb3);
            } else {
                *(uint4*)(&Bs[row * 72 + kk]) = ub0;
                *(uint4*)(&Bs[row * 72 + kk + 8]) = ub1;
            }
            __syncthreads();
            if (s + 1 < 28) { loadA(s + 1); loadB(s + 1); }
#pragma unroll
            for (int k2 = 0; k2 < 64; k2 += 32) {
                const short8 af = *(const short8*)(&As[(16 * w + l16) * 72 + k2 + quad * 8]);
#pragma unroll
                for (int c = 0; c < 4; ++c) {
                    const short8 bfr = *(const short8*)(&Bs[(16 * c + l16) * 72 + k2 + quad * 8]);
                    acc[c] = __builtin_amdgcn_mfma_f32_16x16x32_bf16(af, bfr, acc[c], 0, 0, 0);
                }
            }
        }
#pragma unroll
        for (int c = 0; c < 4; ++c)
#pragma unroll
            for (int r = 0; r < 4; ++r) {
                const int il = 16 * w + quad * 4 + r;
                const int ol = 16 * c + l16;
                out[((size_t)b * Ss + it * 64 + il) * Hh + ot * 64 + ol] = acc[c][r];
            }
    }
}

extern "C" void kernel_launch(void* const* d_in, const int* in_sizes, int n_in,
                              void* d_out, int out_size, void* d_ws, size_t ws_size,
                              hipStream_t stream) {
    const float* h = (const float*)d_in[0];       // [4,256,768] fp32
    const int* rels = (const int*)d_in[1];        // [4,256,256] i32
    const float* basic = (const float*)d_in[2];   // [4,768,768] fp32
    const float* relw = (const float*)d_in[3];    // [64,4] fp32
    const float* selfw = (const float*)d_in[4];   // [768,768] fp32 (out,in)
    float* out = (float*)d_out;                   // [4,256,768] fp32

    // ws layout (u16 elems, 16B-aligned)
    u16* basicT = (u16*)d_ws;                          // 2,359,296
    u16* coefC = basicT + (size_t)4 * Hh * Hh;         // 1,048,576
    u16* Gt = coefC + (size_t)Bb * 4 * Ss * Ss;        // 3,145,728  [bk][o][j]
    int* bar = (int*)(Gt + (size_t)Bb * 4 * Hh * Ss);  // 65 ints: [0]=init,[32]=arrive,[64]=flag

    k_prep2<<<3328, 256, 0, stream>>>(rels, basic, relw, basicT, coefC);
    k_fused2<<<GRID2, 256, 0, stream>>>(h, selfw, basicT, coefC, Gt, bar, out);
}